// Round 12
// baseline (141.055 us; speedup 1.0000x reference)
//
#include <hip/hip_runtime.h>
#include <math.h>

#define K_TOP 512
#define CAND_CAP 3072

struct LvlC {
  int H, lgH, HH, lgHH;
  float fs, wsc, hsc, wex, hex, pwlo, pwhi, phlo, phhi, minwh, maxwh;
};

__device__ const LvlC LVL[4] = {
  {128, 7, 16384, 14, 0.25f,    0.8f, 1.0f, 0.2f, 0.4f, 0.008f, 0.054f, 0.008f, 0.072f, 0.005f, 0.12f},
  { 64, 6,  4096, 12, 0.125f,   0.9f, 1.2f, 0.3f, 0.6f, 0.016f, 0.072f, 0.016f, 0.096f, 0.01f,  0.16f},
  { 32, 5,  1024, 10, 0.0625f,  1.0f, 1.4f, 0.4f, 0.8f, 0.024f, 0.09f,  0.024f, 0.12f,  0.015f, 0.2f },
  { 16, 4,   256,  8, 0.03125f, 1.1f, 1.6f, 0.5f, 1.0f, 0.032f, 0.108f, 0.032f, 0.144f, 0.02f,  0.24f},
};

// fixed candidate thresholds on sort_key (score in (0,1), invalid = -1).
// expected counts/segment: ~1510 / ~1460 / ~1870 / 768 — 26+ sigma inside [512, 3072].
// selmaskscan falls back to exact full-N radix if a count ever lands outside.
__device__ const float TSEL[4] = {0.91f, 0.85f, 0.65f, -2.0f};

// rimg = 1/image_size, image_size = 512 = 2^9: multiply by exact 2^-9 == divide (IEEE exact).
__device__ __forceinline__ void decode_box(const LvlC& L, const float* __restrict__ boxp,
                                           const float* __restrict__ ancp,
                                           int b, int idx, float rimg,
                                           float& x0, float& y0, float& x1, float& y1)
{
#pragma clang fp contract(off)
  int a   = idx >> L.lgHH;
  int rem = idx & (L.HH - 1);
  const float* bp = boxp + (size_t)((b * 3 + a) * 4) * L.HH + rem;
  float d0 = bp[0], d1 = bp[L.HH], d2 = bp[2 * L.HH], d3 = bp[3 * L.HH];
  float4 av = reinterpret_cast<const float4*>(ancp)[idx];
  float a0 = av.x, a1 = av.y, a2 = av.z, a3 = av.w;
  float aw  = (a2 - a0) * rimg;
  float ah  = (a3 - a1) * rimg;
  float acx = (a0 + a2) * 0.5f * rimg;
  float acy = (a1 + a3) * 0.5f * rimg;
  float dx = fminf(fmaxf(d0 * 0.2f, -1.f), 1.f) * L.fs * aw;
  float dy = fminf(fmaxf(d1 * 0.2f, -1.f), 1.f) * L.fs * ah;
  float cx = fminf(fmaxf(acx + dx, 0.f), 1.f);
  float cy = fminf(fmaxf(acy + dy, 0.f), 1.f);
  float dw = fminf(fmaxf(d2 * 0.2f, -2.f), 2.f);
  float dh = fminf(fmaxf(d3 * 0.2f, -2.f), 2.f);
  float pw = fminf(fmaxf(aw * L.wsc * expf(dw * L.wex), L.pwlo), L.pwhi);
  float ph = fminf(fmaxf(ah * L.hsc * expf(dh * L.hex), L.phlo), L.phhi);
  x0 = fminf(fmaxf(cx - 0.5f * pw, 0.f), 1.f);
  y0 = fminf(fmaxf(cy - 0.5f * ph, 0.f), 1.f);
  x1 = fminf(fmaxf(cx + 0.5f * pw, 0.f), 1.f);
  y1 = fminf(fmaxf(cy + 0.5f * ph, 0.f), 1.f);
}

__device__ __forceinline__ void seg_map(int blk, int& b, int& l, int& base, int& iblk)
{
  b = blk / 255;                 // 255 units per batch (65280/256)
  int rb = blk - b * 255;
  if (rb < 192)      { l = 0; iblk = rb;       base = 0;     }
  else if (rb < 240) { l = 1; iblk = rb - 192; base = 49152; }
  else if (rb < 252) { l = 2; iblk = rb - 240; base = 61440; }
  else               { l = 3; iblk = rb - 252; base = 64512; }
}

// ========== Kernel 1: decode all anchors -> keys; threshold-compact candidates ==========
__global__ __launch_bounds__(256) void dc_kernel(
    const float* __restrict__ cls0, const float* __restrict__ box0, const float* __restrict__ anc0,
    const float* __restrict__ cls1, const float* __restrict__ box1, const float* __restrict__ anc1,
    const float* __restrict__ cls2, const float* __restrict__ box2, const float* __restrict__ anc2,
    const float* __restrict__ cls3, const float* __restrict__ box3, const float* __restrict__ anc3,
    const int* __restrict__ imgp, unsigned long long* __restrict__ keys,
    unsigned long long* __restrict__ cand, unsigned* __restrict__ unitCnt,
    unsigned* __restrict__ segDone)
{
  __shared__ unsigned wcnt[4];
  int unit = (int)blockIdx.x;
  int tid = (int)threadIdx.x;
  int wid = tid >> 6, lane = tid & 63;

  if (unit == 0 && tid < 16) segDone[tid * 16] = 0u;   // zero padded counters (stream-ordered)

  int b, l, base, iblk;
  seg_map(unit, b, l, base, iblk);
  int i = iblk * 256 + tid;

  const float *cls, *boxp, *ancp;
  switch (l) {
    case 0:  cls = cls0; boxp = box0; ancp = anc0; break;
    case 1:  cls = cls1; boxp = box1; ancp = anc1; break;
    case 2:  cls = cls2; boxp = box2; ancp = anc2; break;
    default: cls = cls3; boxp = box3; ancp = anc3; break;
  }
  LvlC L = LVL[l];
  float rimg = 1.0f / (float)(*imgp);

  int a   = i >> L.lgHH;
  int rem = i & (L.HH - 1);
  const float* cp = cls + (size_t)((b * 3 + a) * 3) * L.HH + rem;
  float c0 = cp[0], c1 = cp[L.HH], c2 = cp[2 * L.HH];
  float m = c0; int mc = 0;
  if (c1 > m) { m = c1; mc = 1; }
  if (c2 > m) { m = c2; mc = 2; }
  float ms = 1.f / (1.f + expf(-m));   // max of sigmoids == sigmoid of max logit

  float x0, y0, x1, y1;
  decode_box(L, boxp, ancp, b, i, rimg, x0, y0, x1, y1);
  float w = x1 - x0, h = y1 - y0;
  bool valid = (ms > 0.15f) && (w > L.minwh) && (h > L.minwh) && (w < L.maxwh) && (h < L.maxwh);

  float sk = valid ? ms : -1.0f;
  unsigned u = __float_as_uint(sk);
  unsigned ascu  = (u & 0x80000000u) ? ~u : (u | 0x80000000u);
  unsigned descu = ~ascu;
  unsigned long long key = ((unsigned long long)descu << 32)
                         | ((unsigned long long)(unsigned)i << 16)
                         | ((unsigned)mc << 8) | (valid ? 1u : 0u);
  keys[(size_t)b * 65280 + base + i] = key;

  bool take = (sk >= TSEL[l]);
  unsigned long long bm = __ballot(take);
  if (lane == 0) wcnt[wid] = (unsigned)__popcll(bm);
  __syncthreads();
  if (take) {
    unsigned off = 0;
    for (int w2 = 0; w2 < wid; ++w2) off += wcnt[w2];
    off += (unsigned)__popcll(bm & ((1ull << lane) - 1ull));
    cand[(size_t)unit * 256 + off] = key;
  }
  if (tid == 0) unitCnt[unit] = wcnt[0] + wcnt[1] + wcnt[2] + wcnt[3];
}

// ========== Kernel 2: redundant top-512 + 16 mask rows/sub-block; LAST sub-block scans ==========
// 32 sub-blocks per segment each compute the IDENTICAL selection (deterministic), decode boxes
// to LDS, write 16 transposed mask rows (agent-scope stores). The last-arriving sub-block
// (ACQ_REL fetch_add on segDone) loads all masks (agent-scope loads) and runs the Jacobi-
// fixpoint greedy NMS + output write from its own registers/LDS. No spin -> no deadlock.
__global__ __launch_bounds__(512) void selmaskscan_kernel(
    const unsigned long long* __restrict__ keys,
    const unsigned long long* __restrict__ cand, const unsigned* __restrict__ unitCnt,
    const float* __restrict__ box0, const float* __restrict__ anc0,
    const float* __restrict__ box1, const float* __restrict__ anc1,
    const float* __restrict__ box2, const float* __restrict__ anc2,
    const float* __restrict__ box3, const float* __restrict__ anc3,
    const int* __restrict__ imgp,
    unsigned long long* __restrict__ masks, unsigned* __restrict__ segDone,
    float* __restrict__ out)
{
  union BigU {
    struct {
      unsigned long long scand[CAND_CAP];   // 24 KB (selection)
      unsigned hist[8][256];                // 8 KB  (selection)
    } a;
    unsigned long long sMaskT[8 * K_TOP];   // 32 KB (scan phase; overlay)
  };
  __shared__ BigU bu;
  __shared__ float4 sBox[K_TOP];                  // 8 KB
  __shared__ unsigned long long skey[K_TOP];      // 4 KB
  __shared__ unsigned long long skey2[K_TOP];     // 4 KB
  __shared__ unsigned upref[256];
  __shared__ unsigned ucnt_s[256];
  __shared__ unsigned waveSum[8];
  __shared__ unsigned long long shPrefix;
  __shared__ unsigned shBelow, shCnt, shTotal, shLast;
  __shared__ unsigned long long keepWords[8];
  __shared__ unsigned sChanged;

  int blk = (int)blockIdx.x;
  int seg = blk >> 5;            // 32 sub-blocks per segment
  int sub = blk & 31;
  int b = seg >> 2, l = seg & 3;
  int tid = (int)threadIdx.x;
  const int nt = 512;
  int wid = tid >> 6, lane = tid & 63;

  const int nArr[4]    = {49152, 12288, 3072, 768};
  const int baseArr[4] = {0, 49152, 61440, 64512};
  const int nuArr[4]   = {192, 48, 12, 3};
  const int fuArr[4]   = {0, 192, 240, 252};
  int N = nArr[l];
  int nu = nuArr[l];
  int firstU = b * 255 + fuArr[l];
  const unsigned long long* kp = keys + (size_t)b * 65280 + baseArr[l];

  if (tid == 0) { shPrefix = 0ull; shBelow = 0u; shCnt = 0u; }

  // ---- per-unit counts + prefix scan ----
  unsigned c = (tid < nu) ? unitCnt[firstU + tid] : 0u;
  if (tid < 256) ucnt_s[tid] = c;
  unsigned incl = c;
  for (int off = 1; off < 64; off <<= 1) {
    unsigned n = __shfl_up(incl, off);
    if (lane >= off) incl += n;
  }
  if (lane == 63) waveSum[wid] = incl;
  __syncthreads();
  if (tid < 256) {
    unsigned add = 0;
    for (int w2 = 0; w2 < wid; ++w2) add += waveSum[w2];
    if (tid < nu) upref[tid] = incl - c + add;
  }
  if (tid == 0) shTotal = waveSum[0] + waveSum[1] + waveSum[2] + waveSum[3];
  __syncthreads();

  unsigned total = shTotal;
  bool useCand = (total >= K_TOP && total <= CAND_CAP);
  int M = useCand ? (int)total : N;

  // ---- gather candidates to LDS: flat index + binary search ----
  if (useCand) {
    for (int f = tid; f < (int)total; f += nt) {
      int lo = 0, hi = nu - 1;
      while (lo < hi) {
        int mid = (lo + hi + 1) >> 1;
        if ((int)upref[mid] <= f) lo = mid; else hi = mid - 1;
      }
      bu.a.scand[f] = cand[(size_t)(firstU + lo) * 256 + (unsigned)(f - (int)upref[lo])];
    }
  }
  __syncthreads();

  // ---- 6-round radix select (bits 63..16; top-48 unique per segment) ----
  for (int r = 0; r < 6; ++r) {
    int shift = 56 - 8 * r;
    for (int v = tid; v < 8 * 256; v += nt) ((unsigned*)bu.a.hist)[v] = 0u;
    __syncthreads();
    unsigned long long pref = shPrefix;
    unsigned below = shBelow;
    unsigned long long hiMask = (r == 0) ? 0ull : (~0ull << (64 - 8 * r));
    for (int t = tid; t < M; t += nt) {
      unsigned long long k = useCand ? bu.a.scand[t] : kp[t];
      if ((k & hiMask) == (pref & hiMask))
        atomicAdd(&bu.a.hist[wid][(unsigned)((k >> shift) & 0xFF)], 1u);
    }
    __syncthreads();
    unsigned s = 0, incl2 = 0;
    if (tid < 256) {
#pragma unroll
      for (int w2 = 0; w2 < 8; ++w2) s += bu.a.hist[w2][tid];
      incl2 = s;
    }
    for (int off = 1; off < 64; off <<= 1) {
      unsigned n = __shfl_up(incl2, off);
      if (lane >= off) incl2 += n;
    }
    if (lane == 63) waveSum[wid] = incl2;
    __syncthreads();
    if (tid < 256) {
      unsigned add = 0;
      for (int w2 = 0; w2 < wid; ++w2) add += waveSum[w2];
      unsigned inclT = incl2 + add;
      unsigned exclT = inclT - s;
      if (below + exclT < K_TOP && below + inclT >= K_TOP) {
        shBelow = below + exclT;
        shPrefix = pref | ((unsigned long long)(unsigned)tid << shift);
      }
    }
    __syncthreads();
  }
  unsigned long long kth = shPrefix | 0xFFFFull;

  // ---- collect exactly 512 keys <= kth (ballot-aggregated) ----
  for (int t = tid; t < M; t += nt) {
    unsigned long long k = useCand ? bu.a.scand[t] : kp[t];
    bool take = (k <= kth);
    unsigned long long bm = __ballot(take);
    unsigned bp = 0;
    if (lane == 0 && bm) bp = atomicAdd(&shCnt, (unsigned)__popcll(bm));
    bp = __shfl(bp, 0);
    if (take) skey[bp + (unsigned)__popcll(bm & ((1ull << lane) - 1ull))] = k;
  }
  __syncthreads();

  // ---- rank-scatter into sorted order (keys unique -> canonical result) ----
  {
    unsigned long long mykey = skey[tid];
    int rank = 0;
#pragma unroll 8
    for (int j = 0; j < K_TOP; ++j) rank += (skey[j] < mykey) ? 1 : 0;
    skey2[rank] = mykey;
  }
  __syncthreads();

  // ---- decode selected boxes; boxes to LDS, meta in regs ----
  const float *boxp, *ancp;
  switch (l) {
    case 0:  boxp = box0; ancp = anc0; break;
    case 1:  boxp = box1; ancp = anc1; break;
    case 2:  boxp = box2; ancp = anc2; break;
    default: boxp = box3; ancp = anc3; break;
  }
  LvlC L = LVL[l];
  float rimg = 1.0f / (float)(*imgp);
  float myScore; int myLabel; bool myValid;
  {
    unsigned long long key = skey2[tid];
    int idx = (int)((key >> 16) & 0xFFFFull);
    unsigned descu = (unsigned)(key >> 32);
    unsigned ascu  = ~descu;
    unsigned u = (ascu & 0x80000000u) ? (ascu & 0x7FFFFFFFu) : ~ascu;
    myScore = __uint_as_float(u);
    myLabel = (int)((key >> 8) & 0xFFull);
    myValid = (key & 1ull) != 0ull;
    float x0, y0, x1, y1;
    decode_box(L, boxp, ancp, b, idx, rimg, x0, y0, x1, y1);
    float4 bb; bb.x = x0; bb.y = y0; bb.z = x1; bb.w = y1;
    sBox[tid] = bb;
  }
  __syncthreads();

  // ---- mask: this sub-block's 16 rows (wave wid -> rows sub*16 + wid*2 + {0,1}) ----
  {
#pragma clang fp contract(off)
    unsigned long long* mseg = masks + (size_t)seg * K_TOP * 8;
    float4 bj[8]; float aj[8];
#pragma unroll
    for (int cc = 0; cc < 8; ++cc) {
      bj[cc] = sBox[cc * 64 + lane];
      aj[cc] = (bj[cc].z - bj[cc].x) * (bj[cc].w - bj[cc].y);
    }
#pragma unroll
    for (int rr = 0; rr < 2; ++rr) {
      int r = sub * 16 + wid * 2 + rr;
      float4 br = sBox[r];
      float ar_ = (br.z - br.x) * (br.w - br.y);
#pragma unroll
      for (int cc = 0; cc < 8; ++cc) {
        float ltx = fmaxf(br.x, bj[cc].x), lty = fmaxf(br.y, bj[cc].y);
        float rbx = fminf(br.z, bj[cc].z), rby = fminf(br.w, bj[cc].w);
        float ww = fmaxf(rbx - ltx, 0.f), hh = fmaxf(rby - lty, 0.f);
        float inter = ww * hh;
        float iou = inter / (ar_ + aj[cc] - inter + 1e-9f);
        unsigned long long bal = __ballot(iou > 0.5f);
        if (lane == 0)
          __hip_atomic_store(&mseg[cc * K_TOP + r], bal,
                             __ATOMIC_RELAXED, __HIP_MEMORY_SCOPE_AGENT);
      }
    }
  }
  __syncthreads();   // all mask stores drained (vmcnt0 before barrier)

  // ---- last-arriving sub-block per segment does the scan ----
  if (tid == 0) {
    __threadfence();  // belt-and-braces agent release covering all block writes
    unsigned old = __hip_atomic_fetch_add(&segDone[seg * 16], 1u,
                                          __ATOMIC_ACQ_REL, __HIP_MEMORY_SCOPE_AGENT);
    shLast = (old == 31u) ? 1u : 0u;
  }
  __syncthreads();
  if (shLast == 0u) return;
  if (tid == 0) __threadfence();  // acquire: invalidate stale L1/L2 before mask loads
  __syncthreads();

  // ---- load all masks (agent-scope loads, overlay onto selection LDS) ----
  {
    const unsigned long long* mseg = masks + (size_t)seg * K_TOP * 8;
#pragma unroll
    for (int w = 0; w < 8; ++w)
      bu.sMaskT[w * K_TOP + tid] = __hip_atomic_load(&mseg[w * K_TOP + tid],
                                                     __ATOMIC_RELAXED, __HIP_MEMORY_SCOPE_AGENT);
  }

  // init keep = valid
  unsigned long long myWord = __ballot(myValid);
  if (lane == 0) keepWords[wid] = myWord;
  __syncthreads();

  // ---- Jacobi fixpoint: unique fixpoint == greedy NMS (typ. ~5 rounds, bound 513) ----
  for (int it = 0; it < 513; ++it) {
    unsigned long long sup = 0ull;
    for (int w = 0; w < wid; ++w)
      sup |= bu.sMaskT[w * K_TOP + tid] & keepWords[w];
    sup |= bu.sMaskT[wid * K_TOP + tid] & keepWords[wid] & ((1ull << lane) - 1ull);
    bool nk = myValid && (sup == 0ull);
    unsigned long long nw = __ballot(nk);
    __syncthreads();                      // all reads of keepWords done
    if (tid == 0) sChanged = 0u;
    __syncthreads();
    if (lane == 0) {
      if (nw != keepWords[wid]) sChanged = 1u;
      keepWords[wid] = nw;
    }
    __syncthreads();
    if (sChanged == 0u) break;
  }

  // ---- outputs (from own LDS/regs) ----
  {
    int o = seg * K_TOP + tid;
    bool keep = (keepWords[wid] >> lane) & 1ull;
    float4 bx = sBox[tid];
    float4 ob;
    ob.x = keep ? bx.x : 0.f;
    ob.y = keep ? bx.y : 0.f;
    ob.z = keep ? bx.z : 0.f;
    ob.w = keep ? bx.w : 0.f;
    reinterpret_cast<float4*>(out)[o] = ob;                  // boxes:  [0,      32768)
    out[32768 + o] = keep ? myScore : 0.f;                   // scores: [32768,  40960)
    out[40960 + o] = keep ? (float)(myLabel + 1) : 0.f;      // labels: [40960,  49152)
    out[49152 + o] = keep ? 1.f : 0.f;                       // keep:   [49152,  57344)
  }
}

extern "C" void kernel_launch(void* const* d_in, const int* in_sizes, int n_in,
                              void* d_out, int out_size, void* d_ws, size_t ws_size,
                              hipStream_t stream)
{
  const float* cls0 = (const float*)d_in[0];
  const float* box0 = (const float*)d_in[1];
  const float* anc0 = (const float*)d_in[2];
  const float* cls1 = (const float*)d_in[3];
  const float* box1 = (const float*)d_in[4];
  const float* anc1 = (const float*)d_in[5];
  const float* cls2 = (const float*)d_in[6];
  const float* box2 = (const float*)d_in[7];
  const float* anc2 = (const float*)d_in[8];
  const float* cls3 = (const float*)d_in[9];
  const float* box3 = (const float*)d_in[10];
  const float* anc3 = (const float*)d_in[11];
  const int*   imgp = (const int*)d_in[12];

  // ws layout (bytes) — segDone zeroed by dc_kernel (stream-ordered):
  char* ws = (char*)d_ws;
  unsigned long long* keys    = (unsigned long long*)(ws + 0);         // 2,088,960
  unsigned long long* cand    = (unsigned long long*)(ws + 2088960);   // 2,088,960
  unsigned*           unitCnt = (unsigned*)(ws + 4177920);             // 4,096
  unsigned long long* masks   = (unsigned long long*)(ws + 4182016);   // 524,288
  unsigned*           segDone = (unsigned*)(ws + 4706304);             // 1,024 (16 x 64B)
  float* out = (float*)d_out;

  dc_kernel<<<1020, 256, 0, stream>>>(cls0, box0, anc0, cls1, box1, anc1,
                                      cls2, box2, anc2, cls3, box3, anc3,
                                      imgp, keys, cand, unitCnt, segDone);
  selmaskscan_kernel<<<512, 512, 0, stream>>>(keys, cand, unitCnt,
                                              box0, anc0, box1, anc1, box2, anc2, box3, anc3,
                                              imgp, masks, segDone, out);
}

// Round 13
// 117.769 us; speedup vs baseline: 1.1977x; 1.1977x over previous
//
#include <hip/hip_runtime.h>
#include <math.h>

#define K_TOP 512
#define CAND_CAP 3072

struct LvlC {
  int H, lgH, HH, lgHH;
  float fs, wsc, hsc, wex, hex, pwlo, pwhi, phlo, phhi, minwh, maxwh;
};

__device__ const LvlC LVL[4] = {
  {128, 7, 16384, 14, 0.25f,    0.8f, 1.0f, 0.2f, 0.4f, 0.008f, 0.054f, 0.008f, 0.072f, 0.005f, 0.12f},
  { 64, 6,  4096, 12, 0.125f,   0.9f, 1.2f, 0.3f, 0.6f, 0.016f, 0.072f, 0.016f, 0.096f, 0.01f,  0.16f},
  { 32, 5,  1024, 10, 0.0625f,  1.0f, 1.4f, 0.4f, 0.8f, 0.024f, 0.09f,  0.024f, 0.12f,  0.015f, 0.2f },
  { 16, 4,   256,  8, 0.03125f, 1.1f, 1.6f, 0.5f, 1.0f, 0.032f, 0.108f, 0.032f, 0.144f, 0.02f,  0.24f},
};

// fixed candidate thresholds on sort_key (score in (0,1), invalid = -1).
// expected counts/segment: ~1510 / ~1460 / ~1870 / 768 — 26+ sigma inside [512, 3072].
// sel kernel falls back to exact full-N radix if a count ever lands outside.
__device__ const float TSEL[4] = {0.91f, 0.85f, 0.65f, -2.0f};

// rimg = 1/image_size, image_size = 512 = 2^9: multiply by exact 2^-9 == divide (IEEE exact).
__device__ __forceinline__ void decode_box(const LvlC& L, const float* __restrict__ boxp,
                                           const float* __restrict__ ancp,
                                           int b, int idx, float rimg,
                                           float& x0, float& y0, float& x1, float& y1)
{
#pragma clang fp contract(off)
  int a   = idx >> L.lgHH;
  int rem = idx & (L.HH - 1);
  const float* bp = boxp + (size_t)((b * 3 + a) * 4) * L.HH + rem;
  float d0 = bp[0], d1 = bp[L.HH], d2 = bp[2 * L.HH], d3 = bp[3 * L.HH];
  float4 av = reinterpret_cast<const float4*>(ancp)[idx];
  float a0 = av.x, a1 = av.y, a2 = av.z, a3 = av.w;
  float aw  = (a2 - a0) * rimg;
  float ah  = (a3 - a1) * rimg;
  float acx = (a0 + a2) * 0.5f * rimg;
  float acy = (a1 + a3) * 0.5f * rimg;
  float dx = fminf(fmaxf(d0 * 0.2f, -1.f), 1.f) * L.fs * aw;
  float dy = fminf(fmaxf(d1 * 0.2f, -1.f), 1.f) * L.fs * ah;
  float cx = fminf(fmaxf(acx + dx, 0.f), 1.f);
  float cy = fminf(fmaxf(acy + dy, 0.f), 1.f);
  float dw = fminf(fmaxf(d2 * 0.2f, -2.f), 2.f);
  float dh = fminf(fmaxf(d3 * 0.2f, -2.f), 2.f);
  float pw = fminf(fmaxf(aw * L.wsc * expf(dw * L.wex), L.pwlo), L.pwhi);
  float ph = fminf(fmaxf(ah * L.hsc * expf(dh * L.hex), L.phlo), L.phhi);
  x0 = fminf(fmaxf(cx - 0.5f * pw, 0.f), 1.f);
  y0 = fminf(fmaxf(cy - 0.5f * ph, 0.f), 1.f);
  x1 = fminf(fmaxf(cx + 0.5f * pw, 0.f), 1.f);
  y1 = fminf(fmaxf(cy + 0.5f * ph, 0.f), 1.f);
}

__device__ __forceinline__ void seg_map(int blk, int& b, int& l, int& base, int& iblk)
{
  b = blk / 255;                 // 255 units per batch (65280/256)
  int rb = blk - b * 255;
  if (rb < 192)      { l = 0; iblk = rb;       base = 0;     }
  else if (rb < 240) { l = 1; iblk = rb - 192; base = 49152; }
  else if (rb < 252) { l = 2; iblk = rb - 240; base = 61440; }
  else               { l = 3; iblk = rb - 252; base = 64512; }
}

// ========== Kernel 1: decode all anchors -> keys; threshold-compact candidates ==========
__global__ __launch_bounds__(256) void dc_kernel(
    const float* __restrict__ cls0, const float* __restrict__ box0, const float* __restrict__ anc0,
    const float* __restrict__ cls1, const float* __restrict__ box1, const float* __restrict__ anc1,
    const float* __restrict__ cls2, const float* __restrict__ box2, const float* __restrict__ anc2,
    const float* __restrict__ cls3, const float* __restrict__ box3, const float* __restrict__ anc3,
    const int* __restrict__ imgp, unsigned long long* __restrict__ keys,
    unsigned long long* __restrict__ cand, unsigned* __restrict__ unitCnt)
{
  __shared__ unsigned wcnt[4];
  int unit = (int)blockIdx.x;
  int tid = (int)threadIdx.x;
  int wid = tid >> 6, lane = tid & 63;
  int b, l, base, iblk;
  seg_map(unit, b, l, base, iblk);
  int i = iblk * 256 + tid;

  const float *cls, *boxp, *ancp;
  switch (l) {
    case 0:  cls = cls0; boxp = box0; ancp = anc0; break;
    case 1:  cls = cls1; boxp = box1; ancp = anc1; break;
    case 2:  cls = cls2; boxp = box2; ancp = anc2; break;
    default: cls = cls3; boxp = box3; ancp = anc3; break;
  }
  LvlC L = LVL[l];
  float rimg = 1.0f / (float)(*imgp);

  int a   = i >> L.lgHH;
  int rem = i & (L.HH - 1);
  const float* cp = cls + (size_t)((b * 3 + a) * 3) * L.HH + rem;
  float c0 = cp[0], c1 = cp[L.HH], c2 = cp[2 * L.HH];
  float m = c0; int mc = 0;
  if (c1 > m) { m = c1; mc = 1; }
  if (c2 > m) { m = c2; mc = 2; }
  float ms = 1.f / (1.f + expf(-m));   // max of sigmoids == sigmoid of max logit

  float x0, y0, x1, y1;
  decode_box(L, boxp, ancp, b, i, rimg, x0, y0, x1, y1);
  float w = x1 - x0, h = y1 - y0;
  bool valid = (ms > 0.15f) && (w > L.minwh) && (h > L.minwh) && (w < L.maxwh) && (h < L.maxwh);

  float sk = valid ? ms : -1.0f;
  unsigned u = __float_as_uint(sk);
  unsigned ascu  = (u & 0x80000000u) ? ~u : (u | 0x80000000u);
  unsigned descu = ~ascu;
  unsigned long long key = ((unsigned long long)descu << 32)
                         | ((unsigned long long)(unsigned)i << 16)
                         | ((unsigned)mc << 8) | (valid ? 1u : 0u);
  keys[(size_t)b * 65280 + base + i] = key;

  bool take = (sk >= TSEL[l]);
  unsigned long long bm = __ballot(take);
  if (lane == 0) wcnt[wid] = (unsigned)__popcll(bm);
  __syncthreads();
  if (take) {
    unsigned off = 0;
    for (int w2 = 0; w2 < wid; ++w2) off += wcnt[w2];
    off += (unsigned)__popcll(bm & ((1ull << lane) - 1ull));
    cand[(size_t)unit * 256 + off] = key;
  }
  if (tid == 0) unitCnt[unit] = wcnt[0] + wcnt[1] + wcnt[2] + wcnt[3];
}

// ========== Kernel 2: per-segment exact top-512 + decode selected boxes (16 x 512) ==========
__global__ __launch_bounds__(512) void sel_kernel(
    const unsigned long long* __restrict__ keys,
    const unsigned long long* __restrict__ cand, const unsigned* __restrict__ unitCnt,
    const float* __restrict__ box0, const float* __restrict__ anc0,
    const float* __restrict__ box1, const float* __restrict__ anc1,
    const float* __restrict__ box2, const float* __restrict__ anc2,
    const float* __restrict__ box3, const float* __restrict__ anc3,
    const int* __restrict__ imgp,
    float* __restrict__ boxesWS, float* __restrict__ scoresWS,
    int* __restrict__ labelsWS, unsigned* __restrict__ validWS)
{
  __shared__ unsigned long long scand[CAND_CAP];  // 24 KB
  __shared__ unsigned long long skey[K_TOP];      // 4 KB
  __shared__ unsigned long long skey2[K_TOP];     // 4 KB
  __shared__ unsigned hist[8][256];               // 8 KB
  __shared__ unsigned upref[256];
  __shared__ unsigned ucnt_s[256];
  __shared__ unsigned waveSum[8];
  __shared__ unsigned long long shPrefix;
  __shared__ unsigned shBelow, shCnt, shTotal;

  int seg = (int)blockIdx.x;
  int b = seg >> 2, l = seg & 3;
  int tid = (int)threadIdx.x;
  const int nt = 512;
  int wid = tid >> 6, lane = tid & 63;

  const int nArr[4]    = {49152, 12288, 3072, 768};
  const int baseArr[4] = {0, 49152, 61440, 64512};
  const int nuArr[4]   = {192, 48, 12, 3};
  const int fuArr[4]   = {0, 192, 240, 252};
  int N = nArr[l];
  int nu = nuArr[l];
  int firstU = b * 255 + fuArr[l];
  const unsigned long long* kp = keys + (size_t)b * 65280 + baseArr[l];

  if (tid == 0) { shPrefix = 0ull; shBelow = 0u; shCnt = 0u; }

  // ---- one coalesced load of per-unit counts; prefix-scan ----
  unsigned c = (tid < nu) ? unitCnt[firstU + tid] : 0u;
  if (tid < 256) ucnt_s[tid] = c;
  unsigned incl = c;
  for (int off = 1; off < 64; off <<= 1) {
    unsigned n = __shfl_up(incl, off);
    if (lane >= off) incl += n;
  }
  if (lane == 63) waveSum[wid] = incl;
  __syncthreads();
  if (tid < 256) {
    unsigned add = 0;
    for (int w2 = 0; w2 < wid; ++w2) add += waveSum[w2];
    if (tid < nu) upref[tid] = incl - c + add;
  }
  if (tid == 0) shTotal = waveSum[0] + waveSum[1] + waveSum[2] + waveSum[3];
  __syncthreads();

  unsigned total = shTotal;
  bool useCand = (total >= K_TOP && total <= CAND_CAP);
  int M = useCand ? (int)total : N;

  // ---- gather candidates to LDS: flat index + binary search (full lane utilization) ----
  if (useCand) {
    for (int f = tid; f < (int)total; f += nt) {
      int lo = 0, hi = nu - 1;
      while (lo < hi) {
        int mid = (lo + hi + 1) >> 1;
        if ((int)upref[mid] <= f) lo = mid; else hi = mid - 1;
      }
      scand[f] = cand[(size_t)(firstU + lo) * 256 + (unsigned)(f - (int)upref[lo])];
    }
  }
  __syncthreads();

  // ---- 6-round radix select (bits 63..16; top-48 unique per segment) ----
  for (int r = 0; r < 6; ++r) {
    int shift = 56 - 8 * r;
    for (int v = tid; v < 8 * 256; v += nt) ((unsigned*)hist)[v] = 0u;
    __syncthreads();
    unsigned long long pref = shPrefix;
    unsigned below = shBelow;
    unsigned long long hiMask = (r == 0) ? 0ull : (~0ull << (64 - 8 * r));
    for (int t = tid; t < M; t += nt) {
      unsigned long long k = useCand ? scand[t] : kp[t];
      if ((k & hiMask) == (pref & hiMask))
        atomicAdd(&hist[wid][(unsigned)((k >> shift) & 0xFF)], 1u);
    }
    __syncthreads();
    unsigned s = 0, incl2 = 0;
    if (tid < 256) {
#pragma unroll
      for (int w2 = 0; w2 < 8; ++w2) s += hist[w2][tid];
      incl2 = s;
    }
    for (int off = 1; off < 64; off <<= 1) {
      unsigned n = __shfl_up(incl2, off);
      if (lane >= off) incl2 += n;
    }
    if (lane == 63) waveSum[wid] = incl2;
    __syncthreads();
    if (tid < 256) {
      unsigned add = 0;
      for (int w2 = 0; w2 < wid; ++w2) add += waveSum[w2];
      unsigned inclT = incl2 + add;
      unsigned exclT = inclT - s;
      if (below + exclT < K_TOP && below + inclT >= K_TOP) {
        shBelow = below + exclT;
        shPrefix = pref | ((unsigned long long)(unsigned)tid << shift);
      }
    }
    __syncthreads();
  }
  unsigned long long kth = shPrefix | 0xFFFFull;

  // ---- collect exactly 512 keys <= kth (ballot-aggregated) ----
  for (int t = tid; t < M; t += nt) {
    unsigned long long k = useCand ? scand[t] : kp[t];
    bool take = (k <= kth);
    unsigned long long bm = __ballot(take);
    unsigned bp = 0;
    if (lane == 0 && bm) bp = atomicAdd(&shCnt, (unsigned)__popcll(bm));
    bp = __shfl(bp, 0);
    if (take) skey[bp + (unsigned)__popcll(bm & ((1ull << lane) - 1ull))] = k;
  }
  __syncthreads();

  // ---- rank-scatter into sorted order (keys unique) ----
  {
    unsigned long long mykey = skey[tid];
    int rank = 0;
#pragma unroll 8
    for (int j = 0; j < K_TOP; ++j) rank += (skey[j] < mykey) ? 1 : 0;
    skey2[rank] = mykey;
  }
  __syncthreads();

  // ---- decode selected boxes to ws ----
  const float *boxp, *ancp;
  switch (l) {
    case 0:  boxp = box0; ancp = anc0; break;
    case 1:  boxp = box1; ancp = anc1; break;
    case 2:  boxp = box2; ancp = anc2; break;
    default: boxp = box3; ancp = anc3; break;
  }
  LvlC L = LVL[l];
  float rimg = 1.0f / (float)(*imgp);
  {
    unsigned long long key = skey2[tid];
    int idx = (int)((key >> 16) & 0xFFFFull);
    unsigned descu = (unsigned)(key >> 32);
    unsigned ascu  = ~descu;
    unsigned u = (ascu & 0x80000000u) ? (ascu & 0x7FFFFFFFu) : ~ascu;
    float x0, y0, x1, y1;
    decode_box(L, boxp, ancp, b, idx, rimg, x0, y0, x1, y1);
    int o = seg * K_TOP + tid;
    float4 bb; bb.x = x0; bb.y = y0; bb.z = x1; bb.w = y1;
    reinterpret_cast<float4*>(boxesWS)[o] = bb;
    scoresWS[o] = __uint_as_float(u);
    labelsWS[o] = (int)((key >> 8) & 0xFFull);
    validWS[o]  = (unsigned)(key & 1ull);
  }
}

// ========== Kernel 3: IoU>T bitmasks, TRANSPOSED layout masks[seg][word][row] (512 blocks) ==========
__global__ __launch_bounds__(256) void mask_kernel(
    const float* __restrict__ boxesWS, unsigned long long* __restrict__ masks)
{
#pragma clang fp contract(off)
  int blk = (int)blockIdx.x;          // 512 blocks; 32 per segment
  int seg = blk >> 5;
  int wid = (int)threadIdx.x >> 6;    // 4 waves
  int lane = (int)threadIdx.x & 63;
  int waveInSeg = (blk & 31) * 4 + wid;   // 0..127, 4 rows each
  const float4* bb = reinterpret_cast<const float4*>(boxesWS) + seg * K_TOP;
  unsigned long long* mseg = masks + (size_t)seg * K_TOP * 8;

  float4 bj[8]; float aj[8];
#pragma unroll
  for (int c = 0; c < 8; ++c) {
    bj[c] = bb[c * 64 + lane];
    aj[c] = (bj[c].z - bj[c].x) * (bj[c].w - bj[c].y);
  }
#pragma unroll
  for (int rr = 0; rr < 4; ++rr) {
    int r = waveInSeg * 4 + rr;
    float4 br = bb[r];
    float ar_ = (br.z - br.x) * (br.w - br.y);
#pragma unroll
    for (int c = 0; c < 8; ++c) {
      float ltx = fmaxf(br.x, bj[c].x), lty = fmaxf(br.y, bj[c].y);
      float rbx = fminf(br.z, bj[c].z), rby = fminf(br.w, bj[c].w);
      float ww = fmaxf(rbx - ltx, 0.f), hh = fmaxf(rby - lty, 0.f);
      float inter = ww * hh;
      float iou = inter / (ar_ + aj[c] - inter + 1e-9f);
      unsigned long long bal = __ballot(iou > 0.5f);
      if (lane == 0) mseg[c * K_TOP + r] = bal;   // transposed: [word][row]
    }
  }
}

// ========== Kernel 4: Jacobi-fixpoint greedy NMS + output write (16 x 512) ==========
// keep[i] = valid[i] && no kept j<i with m[j][i]. Unique fixpoint == greedy NMS;
// iterate keep <- F(keep) until unchanged (prefix stabilizes; typ. ~5 rounds, bound 513).
__global__ __launch_bounds__(512) void scan_kernel(
    const unsigned long long* __restrict__ masks,
    const float* __restrict__ boxesWS, const float* __restrict__ scoresWS,
    const int* __restrict__ labelsWS, const unsigned* __restrict__ validWS,
    float* __restrict__ out)
{
  __shared__ unsigned long long sMaskT[8 * K_TOP];  // [word][row], 32 KB
  __shared__ unsigned long long keepWords[8];
  __shared__ unsigned sChanged;

  int seg = (int)blockIdx.x;
  int tid = (int)threadIdx.x;
  int wid = tid >> 6, lane = tid & 63;
  const unsigned long long* mp = masks + (size_t)seg * K_TOP * 8;
#pragma unroll
  for (int w = 0; w < 8; ++w) sMaskT[w * K_TOP + tid] = mp[w * K_TOP + tid];  // coalesced
  bool valid = validWS[seg * K_TOP + tid] != 0u;

  // init keep = valid
  unsigned long long myWord = __ballot(valid);
  if (lane == 0) keepWords[wid] = myWord;
  __syncthreads();

  for (int it = 0; it < 513; ++it) {
    unsigned long long sup = 0ull;
    for (int w = 0; w < wid; ++w)
      sup |= sMaskT[w * K_TOP + tid] & keepWords[w];
    sup |= sMaskT[wid * K_TOP + tid] & keepWords[wid] & ((1ull << lane) - 1ull);
    bool nk = valid && (sup == 0ull);
    unsigned long long nw = __ballot(nk);
    __syncthreads();                      // all reads of keepWords done
    if (tid == 0) sChanged = 0u;
    __syncthreads();
    if (lane == 0) {
      if (nw != keepWords[wid]) sChanged = 1u;
      keepWords[wid] = nw;
    }
    __syncthreads();
    if (sChanged == 0u) break;
  }

  // ---- outputs ----
  int o = seg * K_TOP + tid;
  bool keep = (keepWords[wid] >> lane) & 1ull;
  float4 bx = reinterpret_cast<const float4*>(boxesWS)[o];
  float4 ob;
  ob.x = keep ? bx.x : 0.f;
  ob.y = keep ? bx.y : 0.f;
  ob.z = keep ? bx.z : 0.f;
  ob.w = keep ? bx.w : 0.f;
  reinterpret_cast<float4*>(out)[o] = ob;                   // boxes:  [0,      32768)
  out[32768 + o] = keep ? scoresWS[o] : 0.f;                // scores: [32768,  40960)
  out[40960 + o] = keep ? (float)(labelsWS[o] + 1) : 0.f;   // labels: [40960,  49152)
  out[49152 + o] = keep ? 1.f : 0.f;                        // keep:   [49152,  57344)
}

extern "C" void kernel_launch(void* const* d_in, const int* in_sizes, int n_in,
                              void* d_out, int out_size, void* d_ws, size_t ws_size,
                              hipStream_t stream)
{
  const float* cls0 = (const float*)d_in[0];
  const float* box0 = (const float*)d_in[1];
  const float* anc0 = (const float*)d_in[2];
  const float* cls1 = (const float*)d_in[3];
  const float* box1 = (const float*)d_in[4];
  const float* anc1 = (const float*)d_in[5];
  const float* cls2 = (const float*)d_in[6];
  const float* box2 = (const float*)d_in[7];
  const float* anc2 = (const float*)d_in[8];
  const float* cls3 = (const float*)d_in[9];
  const float* box3 = (const float*)d_in[10];
  const float* anc3 = (const float*)d_in[11];
  const int*   imgp = (const int*)d_in[12];

  // ws layout (bytes) — nothing needs pre-zeroing:
  char* ws = (char*)d_ws;
  unsigned long long* keys    = (unsigned long long*)(ws + 0);         // 2,088,960
  unsigned long long* cand    = (unsigned long long*)(ws + 2088960);   // 2,088,960
  unsigned*           unitCnt = (unsigned*)(ws + 4177920);             // 4,096
  float*              boxesWS = (float*)(ws + 4182016);                // 131,072
  float*              scoresWS= (float*)(ws + 4313088);                // 32,768
  int*                labelsWS= (int*)(ws + 4345856);                  // 32,768
  unsigned*           validWS = (unsigned*)(ws + 4378624);             // 32,768
  unsigned long long* masks   = (unsigned long long*)(ws + 4411392);   // 524,288
  float* out = (float*)d_out;

  dc_kernel<<<1020, 256, 0, stream>>>(cls0, box0, anc0, cls1, box1, anc1,
                                      cls2, box2, anc2, cls3, box3, anc3,
                                      imgp, keys, cand, unitCnt);
  sel_kernel<<<16, 512, 0, stream>>>(keys, cand, unitCnt,
                                     box0, anc0, box1, anc1, box2, anc2, box3, anc3,
                                     imgp, boxesWS, scoresWS, labelsWS, validWS);
  mask_kernel<<<512, 256, 0, stream>>>(boxesWS, masks);
  scan_kernel<<<16, 512, 0, stream>>>(masks, boxesWS, scoresWS, labelsWS, validWS, out);
}